// Round 3
// baseline (1035.911 us; speedup 1.0000x reference)
//
#include <hip/hip_runtime.h>
#include <hip/hip_bf16.h>
#include <stdint.h>

#define NODES 50000
#define EDGES 800000

// ---- counting-sort geometry ----
#define EPB 4096                                    // edges per sort block
#define NBLK ((EDGES + EPB - 1) / EPB)              // 196
#define NBUK ((NODES + 63) / 64)                    // 782 coarse buckets (dst>>6)
#define NBUKP 1024                                  // padded (1 bucket / thread @1024)
#define CAP 2560                                    // per-bucket record cap (mean 1023)

#define NTILE (NODES / 16)                          // 3125 row tiles
#define NGB ((NTILE + 15) / 16)                     // 196 gemm blocks @16 waves

typedef short bf16x8 __attribute__((ext_vector_type(8)));
typedef float f32x4 __attribute__((ext_vector_type(4)));

__device__ __forceinline__ unsigned short f2bf(float f) {
    union { float f; unsigned u; } v; v.f = f;
    unsigned r = v.u + 0x7fff + ((v.u >> 16) & 1);   // RNE
    return (unsigned short)(r >> 16);
}
__device__ __forceinline__ float bflo(unsigned hv) {
    union { float f; unsigned u; } v; v.u = hv << 16;
    return v.f;
}
__device__ __forceinline__ float bfhi(unsigned hv) {
    union { float f; unsigned u; } v; v.u = hv & 0xffff0000u;
    return v.f;
}

// ---------------- W pre-swizzle (unchanged) ----------------
__device__ __forceinline__ void wfrag_one(const float* __restrict__ W, unsigned short* Wf,
                                          int idx, int K, int Nn) {
    int NT = Nn >> 4;
    int lane = idx & 63;
    int f = idx >> 6;
    int nt = f % NT;
    int k0 = (f / NT) << 5;
    int n = (nt << 4) + (lane & 15);
    int kk = k0 + ((lane >> 4) << 3);
    unsigned short o[8];
#pragma unroll
    for (int j = 0; j < 8; j++) o[j] = f2bf(W[(kk + j) * Nn + n]);
    ((uint4*)Wf)[idx] = *(uint4*)o;
}

// ---------------- setup: per-block bucket histograms (LDS) + W swizzle -------
__global__ void k_setup_hist(const int* __restrict__ dst, unsigned* __restrict__ hist,
                             int* __restrict__ cursor,
                             const float* __restrict__ W1, unsigned short* Wf1,
                             const float* __restrict__ W2, unsigned short* Wf2,
                             const float* __restrict__ W3, unsigned short* Wf3) {
    if ((int)blockIdx.x < NBLK) {
        __shared__ unsigned cnt[NBUK];
        int t = threadIdx.x;
        for (int i = t; i < NBUK; i += 256) cnt[i] = 0;
        __syncthreads();
        int base = blockIdx.x * EPB;
#pragma unroll
        for (int i = 0; i < EPB / 256; i++) {
            int e = base + i * 256 + t;
            if (e < EDGES) atomicAdd(&cnt[((unsigned)dst[e]) >> 6], 1u);
        }
        __syncthreads();
        for (int b = t; b < NBUK; b += 256) hist[b * NBLK + blockIdx.x] = cnt[b];
    } else {
        int idx = (blockIdx.x - NBLK) * 256 + threadIdx.x;
        if (idx == 0) *cursor = 0;
        if (idx < 4096) wfrag_one(W1, Wf1, idx, 256, 128);
        else if (idx < 6144) wfrag_one(W2, Wf2, idx - 4096, 128, 128);
        else if (idx < 7168) wfrag_one(W3, Wf3, idx - 6144, 128, 64);
    }
}

// ---------------- per-bucket scan across blocks; base claimed order-free -----
__global__ void k_hscan(unsigned* __restrict__ hist, int2* __restrict__ brange,
                        int* __restrict__ cursor) {
    __shared__ int sm[256];
    __shared__ int s_base;
    int b = blockIdx.x, t = threadIdx.x;
    int v = (t < NBLK) ? (int)hist[b * NBLK + t] : 0;
    sm[t] = v;
    __syncthreads();
    for (int off = 1; off < 256; off <<= 1) {
        int x2 = (t >= off) ? sm[t - off] : 0;
        __syncthreads();
        sm[t] += x2;
        __syncthreads();
    }
    int total = sm[255];
    if (t == 0) s_base = atomicAdd(cursor, total);
    __syncthreads();
    if (t < NBLK) hist[b * NBLK + t] = (unsigned)(s_base + sm[t] - v);  // exclusive
    if (t == 0) { int2 r; r.x = s_base; r.y = total; brange[b] = r; }
}

// ---------------- GEMM tile body: swapped-operand MFMA -> coalesced C-store --
// mfma(b, a, acc): C-layout becomes lane&15 = x-row, (lane>>4)*4+r = 4
// CONSECUTIVE w-cols -> one uint2 (4 bf16) store per nt instead of 4 scalar
// 2B stores (4x fewer store ops, 32B coalesced segments).
template <int K, int Nn, bool A_F32>
__device__ __forceinline__ void gemm_tile(const void* __restrict__ A_,
                                          const uint4* __restrict__ Wf,
                                          unsigned short* __restrict__ Hout, int tile) {
    constexpr int NT = Nn / 16;
    int lane = threadIdx.x & 63;
    if (tile * 16 >= NODES) return;
    int row = tile * 16 + (lane & 15);
    int kbase = (lane >> 4) * 8;

    f32x4 acc[NT];
#pragma unroll
    for (int i = 0; i < NT; i++) acc[i] = (f32x4){0.f, 0.f, 0.f, 0.f};

    for (int k0 = 0; k0 < K; k0 += 32) {
        bf16x8 a;
        if (A_F32) {
            const float* A = (const float*)A_;
            const float4* pp = (const float4*)&A[(size_t)row * K + k0 + kbase];
            float4 u0 = pp[0], u1 = pp[1];
            unsigned short t[8];
            t[0] = f2bf(u0.x); t[1] = f2bf(u0.y); t[2] = f2bf(u0.z); t[3] = f2bf(u0.w);
            t[4] = f2bf(u1.x); t[5] = f2bf(u1.y); t[6] = f2bf(u1.z); t[7] = f2bf(u1.w);
            a = *(bf16x8*)t;
        } else {
            const unsigned short* A = (const unsigned short*)A_;
            a = *(const bf16x8*)&A[(size_t)row * K + k0 + kbase];
        }
        int fbase = (k0 >> 5) * NT;
#pragma unroll
        for (int nt = 0; nt < NT; nt++) {
            uint4 braw = Wf[(fbase + nt) * 64 + lane];
            bf16x8 b = *(bf16x8*)&braw;
            acc[nt] = __builtin_amdgcn_mfma_f32_16x16x32_bf16(b, a, acc[nt], 0, 0, 0);
        }
    }
    int xr = lane & 15;
    int wg = lane >> 4;                    // col group (4 cols each)
#pragma unroll
    for (int nt = 0; nt < NT; nt++) {
        uint2 pk;
        pk.x = (unsigned)f2bf(acc[nt][0]) | ((unsigned)f2bf(acc[nt][1]) << 16);
        pk.y = (unsigned)f2bf(acc[nt][2]) | ((unsigned)f2bf(acc[nt][3]) << 16);
        ((uint2*)Hout)[(((size_t)(tile * 16 + xr) * Nn + nt * 16) >> 2) + wg] = pk;
    }
}

// ---------------- fused: LDS bucket sort @1024thr (even) || gemm1 (odd) ------
// 1024 thr/block fixes R2's straggler: serial depth 4x lower, 3136 sort waves.
__global__ __launch_bounds__(1024) void
k_sort_gemm1(const int* __restrict__ src, const int* __restrict__ dst,
             const float* __restrict__ w, const unsigned* __restrict__ gbase,
             int2* __restrict__ rec,
             const float* __restrict__ x, const uint4* __restrict__ Wf1,
             unsigned short* __restrict__ h) {
    __shared__ unsigned long long rec_lds[EPB];   // 32 KB
    __shared__ unsigned cnt[NBUKP];               // 4 KB
    __shared__ unsigned lst[NBUKP];               // 4 KB
    __shared__ unsigned gb[NBUK];                 // 3.1 KB
    __shared__ int sm[1024];                      // 4 KB

    int blk = blockIdx.x;
    int t = threadIdx.x;
    if (blk & 1) {
        gemm_tile<256, 128, true>((const void*)x, Wf1, h, (blk >> 1) * 16 + (t >> 6));
        return;
    }
    int sb = blk >> 1;
    if (t < NBUK) gb[t] = gbase[t * NBLK + sb];
    cnt[t] = 0;
    __syncthreads();

    int base = sb * EPB;
    int nrec = EDGES - base; if (nrec > EPB) nrec = EPB;

    // pass 1: count
#pragma unroll
    for (int i = 0; i < EPB / 1024; i++) {
        int e = base + i * 1024 + t;
        if (e < EDGES) atomicAdd(&cnt[((unsigned)dst[e]) >> 6], 1u);
    }
    __syncthreads();

    // inclusive scan over 1024 buckets (1 per thread)
    int v = (int)cnt[t];
    sm[t] = v;
    __syncthreads();
    for (int off = 1; off < 1024; off <<= 1) {
        int x2 = (t >= off) ? sm[t - off] : 0;
        __syncthreads();
        sm[t] += x2;
        __syncthreads();
    }
    lst[t] = (unsigned)(sm[t] - v);   // exclusive
    cnt[t] = 0;
    __syncthreads();

    // pass 2: rank + stage into LDS in bucket order
#pragma unroll
    for (int i = 0; i < EPB / 1024; i++) {
        int e = base + i * 1024 + t;
        if (e < EDGES) {
            unsigned d = (unsigned)dst[e];
            unsigned b = d >> 6;
            unsigned r = atomicAdd(&cnt[b], 1u);
            unsigned meta = (unsigned)src[e] | ((d & 63u) << 16) | (b << 22);
            rec_lds[lst[b] + r] = (unsigned long long)meta |
                                  ((unsigned long long)__float_as_uint(w[e]) << 32);
        }
    }
    __syncthreads();

    // sweep: per-bucket contiguous runs -> global
    for (int i = t; i < nrec; i += 1024) {
        unsigned long long vv = rec_lds[i];
        unsigned meta = (unsigned)vv;
        unsigned b = meta >> 22;
        unsigned gpos = gb[b] + ((unsigned)i - lst[b]);
        int2 rc; rc.x = (int)(meta & 0x3FFFFFu); rc.y = (int)(vv >> 32);
        rec[gpos] = rc;
    }
}

// ---------------- per-bucket node sort + deg/dis/rsc (unchanged from R2) -----
__global__ void k_sub(int2* __restrict__ rec, const int2* __restrict__ brange,
                      float* __restrict__ dis, int2* __restrict__ rsc) {
    __shared__ int2 stage[CAP];
    __shared__ unsigned short ipos[CAP];
    __shared__ unsigned cnt[64];
    __shared__ unsigned lst[64];
    __shared__ float degw[64];
    int t = threadIdx.x, b = blockIdx.x;
    int2 br = brange[b];
    int base = br.x;
    int n = br.y; if (n > CAP) n = CAP;

    if (t < 64) { cnt[t] = 0; degw[t] = 0.f; }
    __syncthreads();
    for (int i = t; i < n; i += 256) {
        int2 rc = rec[base + i];
        stage[i] = rc;
        unsigned dl = ((unsigned)rc.x >> 16) & 63u;
        atomicAdd(&cnt[dl], 1u);
        atomicAdd(&degw[dl], __int_as_float(rc.y));
    }
    __syncthreads();
    if (t == 0) {
        unsigned run = 0;
        for (int j = 0; j < 64; j++) { lst[j] = run; run += cnt[j]; }
    }
    __syncthreads();
    if (t < 64) {
        int node = b * 64 + t;
        if (node < NODES) {
            dis[node] = rsqrtf(1.0f + degw[t]);            // +1 self-loop
            int2 rs; rs.x = base + (int)lst[t]; rs.y = (int)cnt[t];
            rsc[node] = rs;
        }
    }
    if (t < 64) cnt[t] = 0;
    __syncthreads();
    for (int i = t; i < n; i += 256) {
        unsigned dl = ((unsigned)stage[i].x >> 16) & 63u;
        unsigned r = atomicAdd(&cnt[dl], 1u);
        ipos[lst[dl] + r] = (unsigned short)i;
    }
    __syncthreads();
    for (int i = t; i < n; i += 256) {
        rec[base + i] = stage[ipos[i]];
    }
}

// ---------------- standalone GEMM (layers 2,3) ----------------
template <int K, int Nn, bool A_F32>
__global__ void k_gemm(const void* __restrict__ A_, const uint4* __restrict__ Wf,
                       unsigned short* __restrict__ Hout) {
    gemm_tile<K, Nn, A_F32>(A_, Wf, Hout, blockIdx.x * 4 + (threadIdx.x >> 6));
}

// ---------------- Aggregation: paired-row gathers ----------------
// Half-waves (32 lanes) each gather a DIFFERENT edge's full H row per
// instruction (32 x 8B = 256B @F=128) -> gather instrs halved. One
// __shfl_xor(.,32) cross-half reduce at the end. rec = (src|dlow<<16, w);
// out = dis[d]*(dis[d]*H[d] + sum dis[s]*w*H[s]) + bias.
template <int F, bool RELU, bool OUT_F32>
__global__ void k_agg(const unsigned short* __restrict__ H, const int2* __restrict__ rec,
                      const int2* __restrict__ rsc, const float* __restrict__ dis,
                      const float* __restrict__ bias, void* __restrict__ out_) {
    constexpr int CPL = F / 32;                    // cols per lane: 4 or 2
    int lane = threadIdx.x & 63;
    int l5 = lane & 31;
    int hf = lane >> 5;
    int node = blockIdx.x * 4 + (threadIdx.x >> 6);
    if (node >= NODES) return;
    node = __builtin_amdgcn_readfirstlane(node);

    float dn = dis[node];
    float acc[CPL];
    if (CPL == 4) {
        uint2 hv = ((const uint2*)H)[(size_t)node * 32 + l5];
        acc[0] = bflo(hv.x); acc[1] = bfhi(hv.x);
        acc[2] = bflo(hv.y); acc[3] = bfhi(hv.y);
    } else {
        unsigned hv = ((const unsigned*)H)[(size_t)node * 32 + l5];
        acc[0] = bflo(hv); acc[1] = bfhi(hv);
    }
#pragma unroll
    for (int j = 0; j < CPL; j++) acc[j] = hf ? 0.f : dn * acc[j];   // self-term once

    int2 rs = rsc[node];
    int beg = rs.x, end = rs.x + rs.y;
    int last = end - 1;
    for (int j = beg; j < end; j += 8) {
        int ss[8]; float nn[8];
#pragma unroll
        for (int q = 0; q < 8; q++) {
            int idx = j + q;
            idx = (idx < last) ? idx : last;           // uniform clamp
            int2 rc = rec[idx];                        // scalar load, broadcast
            ss[q] = rc.x & 0xFFFF;
            nn[q] = (j + q < end) ? __int_as_float(rc.y) : 0.0f;
        }
#pragma unroll
        for (int q = 0; q < 8; q++) nn[q] *= dis[ss[q]];
#pragma unroll
        for (int pj = 0; pj < 4; pj++) {
            int srow = hf ? ss[2 * pj + 1] : ss[2 * pj];
            float nw = hf ? nn[2 * pj + 1] : nn[2 * pj];
            if (CPL == 4) {
                uint2 hv = ((const uint2*)H)[(size_t)srow * 32 + l5];
                acc[0] += nw * bflo(hv.x); acc[1] += nw * bfhi(hv.x);
                acc[2] += nw * bflo(hv.y); acc[3] += nw * bfhi(hv.y);
            } else {
                unsigned hv = ((const unsigned*)H)[(size_t)srow * 32 + l5];
                acc[0] += nw * bflo(hv); acc[1] += nw * bfhi(hv);
            }
        }
    }
#pragma unroll
    for (int j = 0; j < CPL; j++) acc[j] += __shfl_xor(acc[j], 32);

    if (hf == 0) {
        if (CPL == 4) {
            float x0 = dn * acc[0] + bias[l5 * 4 + 0];
            float x1 = dn * acc[1] + bias[l5 * 4 + 1];
            float x2 = dn * acc[2] + bias[l5 * 4 + 2];
            float x3 = dn * acc[3] + bias[l5 * 4 + 3];
            if (RELU) {
                x0 = fmaxf(x0, 0.f); x1 = fmaxf(x1, 0.f);
                x2 = fmaxf(x2, 0.f); x3 = fmaxf(x3, 0.f);
            }
            if (OUT_F32) {
                float4 o; o.x = x0; o.y = x1; o.z = x2; o.w = x3;
                ((float4*)out_)[(size_t)node * 32 + l5] = o;
            } else {
                uint2 pk;
                pk.x = (unsigned)f2bf(x0) | ((unsigned)f2bf(x1) << 16);
                pk.y = (unsigned)f2bf(x2) | ((unsigned)f2bf(x3) << 16);
                ((uint2*)out_)[(size_t)node * 32 + l5] = pk;
            }
        } else {
            float x0 = dn * acc[0] + bias[l5 * 2 + 0];
            float x1 = dn * acc[1] + bias[l5 * 2 + 1];
            if (RELU) { x0 = fmaxf(x0, 0.f); x1 = fmaxf(x1, 0.f); }
            if (OUT_F32) {
                float2 o; o.x = x0; o.y = x1;
                ((float2*)out_)[(size_t)node * 32 + l5] = o;
            } else {
                unsigned pk = (unsigned)f2bf(x0) | ((unsigned)f2bf(x1) << 16);
                ((unsigned*)out_)[(size_t)node * 32 + l5] = pk;
            }
        }
    }
}

// ---------------- launch ----------------

extern "C" void kernel_launch(void* const* d_in, const int* in_sizes, int n_in,
                              void* d_out, int out_size, void* d_ws, size_t ws_size,
                              hipStream_t stream) {
    const float* x  = (const float*)d_in[0];
    const int*   ei = (const int*)d_in[1];
    const float* w  = (const float*)d_in[2];
    const float* W1 = (const float*)d_in[3];
    const float* b1 = (const float*)d_in[4];
    const float* W2 = (const float*)d_in[5];
    const float* b2 = (const float*)d_in[6];
    const float* W3 = (const float*)d_in[7];
    const float* b3 = (const float*)d_in[8];
    const int* src = ei;
    const int* dst = ei + EDGES;

    char* p = (char*)d_ws;
    auto alloc = [&](size_t n) { char* r = p; p += (n + 511) & ~(size_t)511; return r; };
    unsigned*       hist   = (unsigned*)alloc((size_t)NBUK * NBLK * 4);
    int2*           brange = (int2*)alloc((size_t)NBUK * 8);
    int*            cursor = (int*)alloc(4);
    int2*           rec    = (int2*)alloc((size_t)EDGES * 8);
    float*          dis    = (float*)alloc(NODES * 4);
    int2*           rsc    = (int2*)alloc((size_t)NODES * 8);
    unsigned short* h      = (unsigned short*)alloc((size_t)NODES * 128 * 2);
    unsigned short* xb     = (unsigned short*)alloc((size_t)NODES * 128 * 2);
    unsigned short* wf1    = (unsigned short*)alloc(256 * 128 * 2);
    unsigned short* wf2    = (unsigned short*)alloc(128 * 128 * 2);
    unsigned short* wf3    = (unsigned short*)alloc(128 * 64 * 2);

    const int TB = 256;

    hipLaunchKernelGGL(k_setup_hist, dim3(NBLK + 28), dim3(TB), 0, stream,
                       dst, hist, cursor, W1, wf1, W2, wf2, W3, wf3);
    hipLaunchKernelGGL(k_hscan, dim3(NBUK), dim3(TB), 0, stream, hist, brange, cursor);
    hipLaunchKernelGGL(k_sort_gemm1, dim3(2 * NBLK), dim3(1024), 0, stream,
                       src, dst, w, hist, rec, x, (const uint4*)wf1, h);
    hipLaunchKernelGGL(k_sub, dim3(NBUK), dim3(TB), 0, stream, rec, brange, dis, rsc);

    int nb_gemm = (NTILE + 3) / 4;        // 782
    int nb_agg  = (NODES + 3) / 4;        // 12500

    // Layer 1 aggregation (gemm1 done in the fused sort launch)
    hipLaunchKernelGGL((k_agg<128, true, false>), dim3(nb_agg), dim3(TB), 0, stream, h, rec, rsc, dis, b1, (void*)xb);

    // Layer 2
    hipLaunchKernelGGL((k_gemm<128, 128, false>), dim3(nb_gemm), dim3(TB), 0, stream, (const void*)xb, (const uint4*)wf2, h);
    hipLaunchKernelGGL((k_agg<128, true, false>), dim3(nb_agg), dim3(TB), 0, stream, h, rec, rsc, dis, b2, (void*)xb);

    // Layer 3 (no relu, fp32 out)
    hipLaunchKernelGGL((k_gemm<128, 64, false>), dim3(nb_gemm), dim3(TB), 0, stream, (const void*)xb, (const uint4*)wf3, h);
    hipLaunchKernelGGL((k_agg<64, false, true>), dim3(nb_agg), dim3(TB), 0, stream, h, rec, rsc, dis, b3, d_out);
}

// Round 4
// 305.695 us; speedup vs baseline: 3.3887x; 3.3887x over previous
//
#include <hip/hip_runtime.h>
#include <hip/hip_bf16.h>
#include <stdint.h>

#define NODES 50000
#define EDGES 800000

// ---- counting-sort geometry ----
#define EPB 4096                                    // edges per sort block
#define NBLK ((EDGES + EPB - 1) / EPB)              // 196
#define NBUK ((NODES + 63) / 64)                    // 782 coarse buckets (dst>>6)
#define NBUKP 1024                                  // padded (1 bucket / thread @1024)
#define CAP 2560                                    // per-bucket record cap (mean 1023)

#define NTILE (NODES / 16)                          // 3125 row tiles

typedef short bf16x8 __attribute__((ext_vector_type(8)));
typedef float f32x4 __attribute__((ext_vector_type(4)));

__device__ __forceinline__ unsigned short f2bf(float f) {
    union { float f; unsigned u; } v; v.f = f;
    unsigned r = v.u + 0x7fff + ((v.u >> 16) & 1);   // RNE
    return (unsigned short)(r >> 16);
}
__device__ __forceinline__ float bf2f(unsigned short h) {
    union { float f; unsigned u; } v; v.u = ((unsigned)h) << 16;
    return v.f;
}
__device__ __forceinline__ float bflo(unsigned hv) {
    union { float f; unsigned u; } v; v.u = hv << 16;
    return v.f;
}
__device__ __forceinline__ float bfhi(unsigned hv) {
    union { float f; unsigned u; } v; v.u = hv & 0xffff0000u;
    return v.f;
}

// ---------------- W pre-swizzle (unchanged) ----------------
__device__ __forceinline__ void wfrag_one(const float* __restrict__ W, unsigned short* Wf,
                                          int idx, int K, int Nn) {
    int NT = Nn >> 4;
    int lane = idx & 63;
    int f = idx >> 6;
    int nt = f % NT;
    int k0 = (f / NT) << 5;
    int n = (nt << 4) + (lane & 15);
    int kk = k0 + ((lane >> 4) << 3);
    unsigned short o[8];
#pragma unroll
    for (int j = 0; j < 8; j++) o[j] = f2bf(W[(kk + j) * Nn + n]);
    ((uint4*)Wf)[idx] = *(uint4*)o;
}

// ---------------- setup: per-block bucket histograms (LDS) + W swizzle -------
__global__ void k_setup_hist(const int* __restrict__ dst, unsigned* __restrict__ hist,
                             int* __restrict__ cursor,
                             const float* __restrict__ W1, unsigned short* Wf1,
                             const float* __restrict__ W2, unsigned short* Wf2,
                             const float* __restrict__ W3, unsigned short* Wf3) {
    if ((int)blockIdx.x < NBLK) {
        __shared__ unsigned cnt[NBUK];
        int t = threadIdx.x;
        for (int i = t; i < NBUK; i += 256) cnt[i] = 0;
        __syncthreads();
        int base = blockIdx.x * EPB;
#pragma unroll
        for (int i = 0; i < EPB / 256; i++) {
            int e = base + i * 256 + t;
            if (e < EDGES) atomicAdd(&cnt[((unsigned)dst[e]) >> 6], 1u);
        }
        __syncthreads();
        for (int b = t; b < NBUK; b += 256) hist[b * NBLK + blockIdx.x] = cnt[b];
    } else {
        int idx = (blockIdx.x - NBLK) * 256 + threadIdx.x;
        if (idx == 0) *cursor = 0;
        if (idx < 4096) wfrag_one(W1, Wf1, idx, 256, 128);
        else if (idx < 6144) wfrag_one(W2, Wf2, idx - 4096, 128, 128);
        else if (idx < 7168) wfrag_one(W3, Wf3, idx - 6144, 128, 64);
    }
}

// ---------------- per-bucket scan across blocks; base claimed order-free -----
__global__ void k_hscan(unsigned* __restrict__ hist, int2* __restrict__ brange,
                        int* __restrict__ cursor) {
    __shared__ int sm[256];
    __shared__ int s_base;
    int b = blockIdx.x, t = threadIdx.x;
    int v = (t < NBLK) ? (int)hist[b * NBLK + t] : 0;
    sm[t] = v;
    __syncthreads();
    for (int off = 1; off < 256; off <<= 1) {
        int x2 = (t >= off) ? sm[t - off] : 0;
        __syncthreads();
        sm[t] += x2;
        __syncthreads();
    }
    int total = sm[255];
    if (t == 0) s_base = atomicAdd(cursor, total);
    __syncthreads();
    if (t < NBLK) hist[b * NBLK + t] = (unsigned)(s_base + sm[t] - v);  // exclusive
    if (t == 0) { int2 r; r.x = s_base; r.y = total; brange[b] = r; }
}

// ---------------- GEMM tile body: swapped-operand MFMA -> coalesced C-store --
// mfma(b, a, acc): lane&15 = x-row, (lane>>4)*4+r = 4 consecutive w-cols ->
// one uint2 (4 bf16) store per nt (harness-verified correct in R3).
template <int K, int Nn, bool A_F32>
__device__ __forceinline__ void gemm_tile(const void* __restrict__ A_,
                                          const uint4* __restrict__ Wf,
                                          unsigned short* __restrict__ Hout, int tile) {
    constexpr int NT = Nn / 16;
    int lane = threadIdx.x & 63;
    if (tile * 16 >= NODES) return;
    int row = tile * 16 + (lane & 15);
    int kbase = (lane >> 4) * 8;

    f32x4 acc[NT];
#pragma unroll
    for (int i = 0; i < NT; i++) acc[i] = (f32x4){0.f, 0.f, 0.f, 0.f};

    for (int k0 = 0; k0 < K; k0 += 32) {
        bf16x8 a;
        if (A_F32) {
            const float* A = (const float*)A_;
            const float4* pp = (const float4*)&A[(size_t)row * K + k0 + kbase];
            float4 u0 = pp[0], u1 = pp[1];
            unsigned short t[8];
            t[0] = f2bf(u0.x); t[1] = f2bf(u0.y); t[2] = f2bf(u0.z); t[3] = f2bf(u0.w);
            t[4] = f2bf(u1.x); t[5] = f2bf(u1.y); t[6] = f2bf(u1.z); t[7] = f2bf(u1.w);
            a = *(bf16x8*)t;
        } else {
            const unsigned short* A = (const unsigned short*)A_;
            a = *(const bf16x8*)&A[(size_t)row * K + k0 + kbase];
        }
        int fbase = (k0 >> 5) * NT;
#pragma unroll
        for (int nt = 0; nt < NT; nt++) {
            uint4 braw = Wf[(fbase + nt) * 64 + lane];
            bf16x8 b = *(bf16x8*)&braw;
            acc[nt] = __builtin_amdgcn_mfma_f32_16x16x32_bf16(b, a, acc[nt], 0, 0, 0);
        }
    }
    int xr = lane & 15;
    int wg = lane >> 4;                    // col group (4 cols each)
#pragma unroll
    for (int nt = 0; nt < NT; nt++) {
        uint2 pk;
        pk.x = (unsigned)f2bf(acc[nt][0]) | ((unsigned)f2bf(acc[nt][1]) << 16);
        pk.y = (unsigned)f2bf(acc[nt][2]) | ((unsigned)f2bf(acc[nt][3]) << 16);
        ((uint2*)Hout)[(((size_t)(tile * 16 + xr) * Nn + nt * 16) >> 2) + wg] = pk;
    }
}

// ---------------- fused: LDS bucket sort @1024thr (even) || gemm1 (odd) ------
__global__ __launch_bounds__(1024) void
k_sort_gemm1(const int* __restrict__ src, const int* __restrict__ dst,
             const float* __restrict__ w, const unsigned* __restrict__ gbase,
             int2* __restrict__ rec,
             const float* __restrict__ x, const uint4* __restrict__ Wf1,
             unsigned short* __restrict__ h) {
    __shared__ unsigned long long rec_lds[EPB];   // 32 KB
    __shared__ unsigned cnt[NBUKP];               // 4 KB
    __shared__ unsigned lst[NBUKP];               // 4 KB
    __shared__ unsigned gb[NBUK];                 // 3.1 KB
    __shared__ int sm[1024];                      // 4 KB

    int blk = blockIdx.x;
    int t = threadIdx.x;
    if (blk & 1) {
        gemm_tile<256, 128, true>((const void*)x, Wf1, h, (blk >> 1) * 16 + (t >> 6));
        return;
    }
    int sb = blk >> 1;
    if (t < NBUK) gb[t] = gbase[t * NBLK + sb];
    cnt[t] = 0;
    __syncthreads();

    int base = sb * EPB;
    int nrec = EDGES - base; if (nrec > EPB) nrec = EPB;

    // pass 1: count
#pragma unroll
    for (int i = 0; i < EPB / 1024; i++) {
        int e = base + i * 1024 + t;
        if (e < EDGES) atomicAdd(&cnt[((unsigned)dst[e]) >> 6], 1u);
    }
    __syncthreads();

    // inclusive scan over 1024 buckets (1 per thread)
    int v = (int)cnt[t];
    sm[t] = v;
    __syncthreads();
    for (int off = 1; off < 1024; off <<= 1) {
        int x2 = (t >= off) ? sm[t - off] : 0;
        __syncthreads();
        sm[t] += x2;
        __syncthreads();
    }
    lst[t] = (unsigned)(sm[t] - v);   // exclusive
    cnt[t] = 0;
    __syncthreads();

    // pass 2: rank + stage into LDS in bucket order
#pragma unroll
    for (int i = 0; i < EPB / 1024; i++) {
        int e = base + i * 1024 + t;
        if (e < EDGES) {
            unsigned d = (unsigned)dst[e];
            unsigned b = d >> 6;
            unsigned r = atomicAdd(&cnt[b], 1u);
            unsigned meta = (unsigned)src[e] | ((d & 63u) << 16) | (b << 22);
            rec_lds[lst[b] + r] = (unsigned long long)meta |
                                  ((unsigned long long)__float_as_uint(w[e]) << 32);
        }
    }
    __syncthreads();

    // sweep: per-bucket contiguous runs -> global
    for (int i = t; i < nrec; i += 1024) {
        unsigned long long vv = rec_lds[i];
        unsigned meta = (unsigned)vv;
        unsigned b = meta >> 22;
        unsigned gpos = gb[b] + ((unsigned)i - lst[b]);
        int2 rc; rc.x = (int)(meta & 0x3FFFFFu); rc.y = (int)(vv >> 32);
        rec[gpos] = rc;
    }
}

// ---------------- per-bucket node sort + deg/dis/rsc ----------------
__global__ void k_sub(int2* __restrict__ rec, const int2* __restrict__ brange,
                      float* __restrict__ dis, int2* __restrict__ rsc) {
    __shared__ int2 stage[CAP];
    __shared__ unsigned short ipos[CAP];
    __shared__ unsigned cnt[64];
    __shared__ unsigned lst[64];
    __shared__ float degw[64];
    int t = threadIdx.x, b = blockIdx.x;
    int2 br = brange[b];
    int base = br.x;
    int n = br.y; if (n > CAP) n = CAP;

    if (t < 64) { cnt[t] = 0; degw[t] = 0.f; }
    __syncthreads();
    for (int i = t; i < n; i += 256) {
        int2 rc = rec[base + i];
        stage[i] = rc;
        unsigned dl = ((unsigned)rc.x >> 16) & 63u;
        atomicAdd(&cnt[dl], 1u);
        atomicAdd(&degw[dl], __int_as_float(rc.y));
    }
    __syncthreads();
    if (t == 0) {
        unsigned run = 0;
        for (int j = 0; j < 64; j++) { lst[j] = run; run += cnt[j]; }
    }
    __syncthreads();
    if (t < 64) {
        int node = b * 64 + t;
        if (node < NODES) {
            dis[node] = rsqrtf(1.0f + degw[t]);            // +1 self-loop
            int2 rs; rs.x = base + (int)lst[t]; rs.y = (int)cnt[t];
            rsc[node] = rs;
        }
    }
    if (t < 64) cnt[t] = 0;
    __syncthreads();
    for (int i = t; i < n; i += 256) {
        unsigned dl = ((unsigned)stage[i].x >> 16) & 63u;
        unsigned r = atomicAdd(&cnt[dl], 1u);
        ipos[lst[dl] + r] = (unsigned short)i;
    }
    __syncthreads();
    for (int i = t; i < n; i += 256) {
        rec[base + i] = stage[ipos[i]];
    }
}

// ---------------- standalone GEMM (layers 2,3) ----------------
template <int K, int Nn, bool A_F32>
__global__ void k_gemm(const void* __restrict__ A_, const uint4* __restrict__ Wf,
                       unsigned short* __restrict__ Hout) {
    gemm_tile<K, Nn, A_F32>(A_, Wf, Hout, blockIdx.x * 4 + (threadIdx.x >> 6));
}

// ---------------- Aggregation (R2-proven structure, reverted verbatim) -------
// One wave per node; records on the scalar path (wave-uniform); full-wave row
// gathers; 8 in flight. rec = (src|dlow<<16, w);
// out = dis[d]*(dis[d]*H[d] + sum dis[s]*w*H[s]) + bias.
template <int F, bool RELU, bool OUT_F32>
__global__ void k_agg(const unsigned short* __restrict__ H, const int2* __restrict__ rec,
                      const int2* __restrict__ rsc, const float* __restrict__ dis,
                      const float* __restrict__ bias, void* __restrict__ out_) {
    constexpr int VPT = F / 64;
    int lane = threadIdx.x & 63;
    int node = blockIdx.x * 4 + (threadIdx.x >> 6);
    if (node >= NODES) return;
    node = __builtin_amdgcn_readfirstlane(node);   // wave-uniform -> SGPR

    const unsigned* H32 = (const unsigned*)H;

    float dn = dis[node];
    float acc0, acc1 = 0.f;
    if (VPT == 2) {
        unsigned hv = H32[node * 64 + lane];
        acc0 = dn * bflo(hv);
        acc1 = dn * bfhi(hv);
    } else {
        acc0 = dn * bf2f(H[node * 64 + lane]);
    }

    int2 rs = rsc[node];
    int beg = rs.x, end = rs.x + rs.y;
    int last = end - 1;
    for (int j = beg; j < end; j += 8) {
        int ss[8]; float nn[8];
#pragma unroll
        for (int q = 0; q < 8; q++) {
            int idx = j + q;
            idx = (idx < last) ? idx : last;           // uniform clamp
            int2 rc = rec[idx];                        // scalar load, broadcast
            ss[q] = rc.x & 0xFFFF;
            nn[q] = (j + q < end) ? __int_as_float(rc.y) : 0.0f;
        }
#pragma unroll
        for (int q = 0; q < 8; q++) nn[q] *= dis[ss[q]];   // broadcast loads
        if (VPT == 2) {
            unsigned hh[8];
#pragma unroll
            for (int q = 0; q < 8; q++) hh[q] = H32[ss[q] * 64 + lane];
#pragma unroll
            for (int q = 0; q < 8; q++) {
                acc0 += nn[q] * bflo(hh[q]);
                acc1 += nn[q] * bfhi(hh[q]);
            }
        } else {
            unsigned short hh[8];
#pragma unroll
            for (int q = 0; q < 8; q++) hh[q] = H[ss[q] * 64 + lane];
#pragma unroll
            for (int q = 0; q < 8; q++) acc0 += nn[q] * bf2f(hh[q]);
        }
    }

    if (OUT_F32) {
        float* out = (float*)out_;
        if (VPT == 2) {
            float x0 = dn * acc0 + bias[lane * 2];
            float x1 = dn * acc1 + bias[lane * 2 + 1];
            if (RELU) { x0 = fmaxf(x0, 0.f); x1 = fmaxf(x1, 0.f); }
            out[(size_t)node * F + lane * 2] = x0;
            out[(size_t)node * F + lane * 2 + 1] = x1;
        } else {
            float x0 = dn * acc0 + bias[lane];
            if (RELU) x0 = fmaxf(x0, 0.f);
            out[(size_t)node * F + lane] = x0;
        }
    } else {
        unsigned short* out = (unsigned short*)out_;
        if (VPT == 2) {
            float x0 = dn * acc0 + bias[lane * 2];
            float x1 = dn * acc1 + bias[lane * 2 + 1];
            if (RELU) { x0 = fmaxf(x0, 0.f); x1 = fmaxf(x1, 0.f); }
            unsigned pk = (unsigned)f2bf(x0) | ((unsigned)f2bf(x1) << 16);
            *(unsigned*)&out[(size_t)node * F + lane * 2] = pk;
        } else {
            float x0 = dn * acc0 + bias[lane];
            if (RELU) x0 = fmaxf(x0, 0.f);
            out[(size_t)node * F + lane] = f2bf(x0);
        }
    }
}

// ---------------- launch ----------------

extern "C" void kernel_launch(void* const* d_in, const int* in_sizes, int n_in,
                              void* d_out, int out_size, void* d_ws, size_t ws_size,
                              hipStream_t stream) {
    const float* x  = (const float*)d_in[0];
    const int*   ei = (const int*)d_in[1];
    const float* w  = (const float*)d_in[2];
    const float* W1 = (const float*)d_in[3];
    const float* b1 = (const float*)d_in[4];
    const float* W2 = (const float*)d_in[5];
    const float* b2 = (const float*)d_in[6];
    const float* W3 = (const float*)d_in[7];
    const float* b3 = (const float*)d_in[8];
    const int* src = ei;
    const int* dst = ei + EDGES;

    char* p = (char*)d_ws;
    auto alloc = [&](size_t n) { char* r = p; p += (n + 511) & ~(size_t)511; return r; };
    unsigned*       hist   = (unsigned*)alloc((size_t)NBUK * NBLK * 4);
    int2*           brange = (int2*)alloc((size_t)NBUK * 8);
    int*            cursor = (int*)alloc(4);
    int2*           rec    = (int2*)alloc((size_t)EDGES * 8);
    float*          dis    = (float*)alloc(NODES * 4);
    int2*           rsc    = (int2*)alloc((size_t)NODES * 8);
    unsigned short* h      = (unsigned short*)alloc((size_t)NODES * 128 * 2);
    unsigned short* xb     = (unsigned short*)alloc((size_t)NODES * 128 * 2);
    unsigned short* wf1    = (unsigned short*)alloc(256 * 128 * 2);
    unsigned short* wf2    = (unsigned short*)alloc(128 * 128 * 2);
    unsigned short* wf3    = (unsigned short*)alloc(128 * 64 * 2);

    const int TB = 256;

    hipLaunchKernelGGL(k_setup_hist, dim3(NBLK + 28), dim3(TB), 0, stream,
                       dst, hist, cursor, W1, wf1, W2, wf2, W3, wf3);
    hipLaunchKernelGGL(k_hscan, dim3(NBUK), dim3(TB), 0, stream, hist, brange, cursor);
    hipLaunchKernelGGL(k_sort_gemm1, dim3(2 * NBLK), dim3(1024), 0, stream,
                       src, dst, w, hist, rec, x, (const uint4*)wf1, h);
    hipLaunchKernelGGL(k_sub, dim3(NBUK), dim3(TB), 0, stream, rec, brange, dis, rsc);

    int nb_gemm = (NTILE + 3) / 4;        // 782
    int nb_agg  = (NODES + 3) / 4;        // 12500

    // Layer 1 aggregation (gemm1 done in the fused sort launch)
    hipLaunchKernelGGL((k_agg<128, true, false>), dim3(nb_agg), dim3(TB), 0, stream, h, rec, rsc, dis, b1, (void*)xb);

    // Layer 2
    hipLaunchKernelGGL((k_gemm<128, 128, false>), dim3(nb_gemm), dim3(TB), 0, stream, (const void*)xb, (const uint4*)wf2, h);
    hipLaunchKernelGGL((k_agg<128, true, false>), dim3(nb_agg), dim3(TB), 0, stream, h, rec, rsc, dis, b2, (void*)xb);

    // Layer 3 (no relu, fp32 out)
    hipLaunchKernelGGL((k_gemm<128, 64, false>), dim3(nb_gemm), dim3(TB), 0, stream, (const void*)xb, (const uint4*)wf3, h);
    hipLaunchKernelGGL((k_agg<64, false, true>), dim3(nb_agg), dim3(TB), 0, stream, h, rec, rsc, dis, b3, d_out);
}

// Round 5
// 296.803 us; speedup vs baseline: 3.4902x; 1.0300x over previous
//
#include <hip/hip_runtime.h>
#include <hip/hip_bf16.h>
#include <stdint.h>

#define NODES 50000
#define EDGES 800000

// ---- counting-sort geometry ----
#define EPB 4096                                    // edges per sort block
#define NBLK ((EDGES + EPB - 1) / EPB)              // 196
#define NBUK ((NODES + 63) / 64)                    // 782 coarse buckets (dst>>6)
#define NBUKP 1024                                  // padded (1 bucket / thread @1024)
#define CAP 2560                                    // per-bucket record cap (mean 1023)

#define NTILE (NODES / 16)                          // 3125 row tiles

typedef short bf16x8 __attribute__((ext_vector_type(8)));
typedef float f32x4 __attribute__((ext_vector_type(4)));

__device__ __forceinline__ unsigned short f2bf(float f) {
    union { float f; unsigned u; } v; v.f = f;
    unsigned r = v.u + 0x7fff + ((v.u >> 16) & 1);   // RNE
    return (unsigned short)(r >> 16);
}
__device__ __forceinline__ float bf2f(unsigned short h) {
    union { float f; unsigned u; } v; v.u = ((unsigned)h) << 16;
    return v.f;
}
__device__ __forceinline__ float bflo(unsigned hv) {
    union { float f; unsigned u; } v; v.u = hv << 16;
    return v.f;
}
__device__ __forceinline__ float bfhi(unsigned hv) {
    union { float f; unsigned u; } v; v.u = hv & 0xffff0000u;
    return v.f;
}

// ---------------- W pre-swizzle (unchanged) ----------------
__device__ __forceinline__ void wfrag_one(const float* __restrict__ W, unsigned short* Wf,
                                          int idx, int K, int Nn) {
    int NT = Nn >> 4;
    int lane = idx & 63;
    int f = idx >> 6;
    int nt = f % NT;
    int k0 = (f / NT) << 5;
    int n = (nt << 4) + (lane & 15);
    int kk = k0 + ((lane >> 4) << 3);
    unsigned short o[8];
#pragma unroll
    for (int j = 0; j < 8; j++) o[j] = f2bf(W[(kk + j) * Nn + n]);
    ((uint4*)Wf)[idx] = *(uint4*)o;
}

// ---------------- setup: per-block bucket histograms (LDS) + W swizzle -------
__global__ void k_setup_hist(const int* __restrict__ dst, unsigned* __restrict__ hist,
                             int* __restrict__ cursor,
                             const float* __restrict__ W1, unsigned short* Wf1,
                             const float* __restrict__ W2, unsigned short* Wf2,
                             const float* __restrict__ W3, unsigned short* Wf3) {
    if ((int)blockIdx.x < NBLK) {
        __shared__ unsigned cnt[NBUK];
        int t = threadIdx.x;
        for (int i = t; i < NBUK; i += 256) cnt[i] = 0;
        __syncthreads();
        int base = blockIdx.x * EPB;
#pragma unroll
        for (int i = 0; i < EPB / 256; i++) {
            int e = base + i * 256 + t;
            if (e < EDGES) atomicAdd(&cnt[((unsigned)dst[e]) >> 6], 1u);
        }
        __syncthreads();
        for (int b = t; b < NBUK; b += 256) hist[b * NBLK + blockIdx.x] = cnt[b];
    } else {
        int idx = (blockIdx.x - NBLK) * 256 + threadIdx.x;
        if (idx == 0) *cursor = 0;
        if (idx < 4096) wfrag_one(W1, Wf1, idx, 256, 128);
        else if (idx < 6144) wfrag_one(W2, Wf2, idx - 4096, 128, 128);
        else if (idx < 7168) wfrag_one(W3, Wf3, idx - 6144, 128, 64);
    }
}

// ---------------- per-bucket scan across blocks ----------------
// Writes cbB[blk*NBUKP + bucket] = {local count, global base} (block-major so
// k_sort loads coalesced), plus brange[bucket]. hist preserved -> k_sort needs
// no recount pass.
__global__ void k_hscan(const unsigned* __restrict__ hist, uint2* __restrict__ cbB,
                        int2* __restrict__ brange, int* __restrict__ cursor) {
    __shared__ int sm[256];
    __shared__ int s_base;
    int b = blockIdx.x, t = threadIdx.x;
    int v = (t < NBLK) ? (int)hist[b * NBLK + t] : 0;
    sm[t] = v;
    __syncthreads();
    for (int off = 1; off < 256; off <<= 1) {
        int x2 = (t >= off) ? sm[t - off] : 0;
        __syncthreads();
        sm[t] += x2;
        __syncthreads();
    }
    int total = sm[255];
    if (t == 0) s_base = atomicAdd(cursor, total);
    __syncthreads();
    if (t < NBLK) {
        uint2 cb; cb.x = (unsigned)v; cb.y = (unsigned)(s_base + sm[t] - v);
        cbB[(size_t)t * NBUKP + b] = cb;
    }
    if (t == 0) { int2 r; r.x = s_base; r.y = total; brange[b] = r; }
}

// ---------------- standalone sort: place edges into dst-bucket order ---------
// Counts come precomputed (cbB); single edge pass + LDS stage + swept writes.
// Wave-shuffle scan: 2 barriers total (vs 20 in R2/R4).
__global__ __launch_bounds__(1024) void
k_sort(const int* __restrict__ src, const int* __restrict__ dst,
       const float* __restrict__ w, const uint2* __restrict__ cbB,
       int2* __restrict__ rec) {
    __shared__ unsigned long long rec_lds[EPB];   // 32 KB
    __shared__ unsigned cnt[NBUKP];               // 4 KB
    __shared__ unsigned lst[NBUKP];               // 4 KB
    __shared__ unsigned gb[NBUKP];                // 4 KB
    __shared__ int wsum[16];

    int sb = blockIdx.x;
    int t = threadIdx.x;
    int lane = t & 63;
    int wid = t >> 6;

    uint2 cb = cbB[(size_t)sb * NBUKP + t];
    int v = (t < NBUK) ? (int)cb.x : 0;
    gb[t] = (t < NBUK) ? cb.y : 0u;

    // wave-level inclusive scan of v
    int incl = v;
#pragma unroll
    for (int d = 1; d < 64; d <<= 1) {
        int y = __shfl_up(incl, d, 64);
        if (lane >= d) incl += y;
    }
    if (lane == 63) wsum[wid] = incl;
    __syncthreads();
    if (wid == 0) {
        int s = (lane < 16) ? wsum[lane] : 0;
#pragma unroll
        for (int d = 1; d < 16; d <<= 1) {
            int y = __shfl_up(s, d, 16);
            if ((lane & 15) >= d) s += y;
        }
        if (lane < 16) wsum[lane] = s;
    }
    cnt[t] = 0;
    __syncthreads();
    int wpre = (wid > 0) ? wsum[wid - 1] : 0;
    lst[t] = (unsigned)(wpre + incl - v);   // block-local exclusive prefix
    __syncthreads();

    int base = sb * EPB;
    int nrec = EDGES - base; if (nrec > EPB) nrec = EPB;

    // rank + stage into LDS in bucket order
#pragma unroll
    for (int i = 0; i < EPB / 1024; i++) {
        int e = base + i * 1024 + t;
        if (e < EDGES) {
            unsigned d = (unsigned)dst[e];
            unsigned b = d >> 6;
            unsigned r = atomicAdd(&cnt[b], 1u);
            unsigned meta = (unsigned)src[e] | ((d & 63u) << 16) | (b << 22);
            rec_lds[lst[b] + r] = (unsigned long long)meta |
                                  ((unsigned long long)__float_as_uint(w[e]) << 32);
        }
    }
    __syncthreads();

    // sweep: per-bucket contiguous runs -> global
    for (int i = t; i < nrec; i += 1024) {
        unsigned long long vv = rec_lds[i];
        unsigned meta = (unsigned)vv;
        unsigned b = meta >> 22;
        unsigned gpos = gb[b] + ((unsigned)i - lst[b]);
        int2 rc; rc.x = (int)(meta & 0x3FFFFFu); rc.y = (int)(vv >> 32);
        rec[gpos] = rc;
    }
}

// ---------------- per-bucket node sort + deg/dis/rsc (unchanged) -------------
__global__ void k_sub(int2* __restrict__ rec, const int2* __restrict__ brange,
                      float* __restrict__ dis, int2* __restrict__ rsc) {
    __shared__ int2 stage[CAP];
    __shared__ unsigned short ipos[CAP];
    __shared__ unsigned cnt[64];
    __shared__ unsigned lst[64];
    __shared__ float degw[64];
    int t = threadIdx.x, b = blockIdx.x;
    int2 br = brange[b];
    int base = br.x;
    int n = br.y; if (n > CAP) n = CAP;

    if (t < 64) { cnt[t] = 0; degw[t] = 0.f; }
    __syncthreads();
    for (int i = t; i < n; i += 256) {
        int2 rc = rec[base + i];
        stage[i] = rc;
        unsigned dl = ((unsigned)rc.x >> 16) & 63u;
        atomicAdd(&cnt[dl], 1u);
        atomicAdd(&degw[dl], __int_as_float(rc.y));
    }
    __syncthreads();
    if (t == 0) {
        unsigned run = 0;
        for (int j = 0; j < 64; j++) { lst[j] = run; run += cnt[j]; }
    }
    __syncthreads();
    if (t < 64) {
        int node = b * 64 + t;
        if (node < NODES) {
            dis[node] = rsqrtf(1.0f + degw[t]);            // +1 self-loop
            int2 rs; rs.x = base + (int)lst[t]; rs.y = (int)cnt[t];
            rsc[node] = rs;
        }
    }
    if (t < 64) cnt[t] = 0;
    __syncthreads();
    for (int i = t; i < n; i += 256) {
        unsigned dl = ((unsigned)stage[i].x >> 16) & 63u;
        unsigned r = atomicAdd(&cnt[dl], 1u);
        ipos[lst[dl] + r] = (unsigned short)i;
    }
    __syncthreads();
    for (int i = t; i < n; i += 256) {
        rec[base + i] = stage[ipos[i]];
    }
}

// ---------------- GEMM tile body: swapped-operand MFMA -> coalesced C-store --
template <int K, int Nn, bool A_F32>
__device__ __forceinline__ void gemm_tile(const void* __restrict__ A_,
                                          const uint4* __restrict__ Wf,
                                          unsigned short* __restrict__ Hout, int tile) {
    constexpr int NT = Nn / 16;
    int lane = threadIdx.x & 63;
    if (tile * 16 >= NODES) return;
    int row = tile * 16 + (lane & 15);
    int kbase = (lane >> 4) * 8;

    f32x4 acc[NT];
#pragma unroll
    for (int i = 0; i < NT; i++) acc[i] = (f32x4){0.f, 0.f, 0.f, 0.f};

    for (int k0 = 0; k0 < K; k0 += 32) {
        bf16x8 a;
        if (A_F32) {
            const float* A = (const float*)A_;
            const float4* pp = (const float4*)&A[(size_t)row * K + k0 + kbase];
            float4 u0 = pp[0], u1 = pp[1];
            unsigned short t[8];
            t[0] = f2bf(u0.x); t[1] = f2bf(u0.y); t[2] = f2bf(u0.z); t[3] = f2bf(u0.w);
            t[4] = f2bf(u1.x); t[5] = f2bf(u1.y); t[6] = f2bf(u1.z); t[7] = f2bf(u1.w);
            a = *(bf16x8*)t;
        } else {
            const unsigned short* A = (const unsigned short*)A_;
            a = *(const bf16x8*)&A[(size_t)row * K + k0 + kbase];
        }
        int fbase = (k0 >> 5) * NT;
#pragma unroll
        for (int nt = 0; nt < NT; nt++) {
            uint4 braw = Wf[(fbase + nt) * 64 + lane];
            bf16x8 b = *(bf16x8*)&braw;
            acc[nt] = __builtin_amdgcn_mfma_f32_16x16x32_bf16(b, a, acc[nt], 0, 0, 0);
        }
    }
    int xr = lane & 15;
    int wg = lane >> 4;                    // col group (4 cols each)
#pragma unroll
    for (int nt = 0; nt < NT; nt++) {
        uint2 pk;
        pk.x = (unsigned)f2bf(acc[nt][0]) | ((unsigned)f2bf(acc[nt][1]) << 16);
        pk.y = (unsigned)f2bf(acc[nt][2]) | ((unsigned)f2bf(acc[nt][3]) << 16);
        ((uint2*)Hout)[(((size_t)(tile * 16 + xr) * Nn + nt * 16) >> 2) + wg] = pk;
    }
}

// ---------------- standalone GEMM (all 3 layers) ----------------
template <int K, int Nn, bool A_F32>
__global__ void k_gemm(const void* __restrict__ A_, const uint4* __restrict__ Wf,
                       unsigned short* __restrict__ Hout) {
    gemm_tile<K, Nn, A_F32>(A_, Wf, Hout, blockIdx.x * 4 + (threadIdx.x >> 6));
}

// ---------------- Aggregation (R2-proven structure, unchanged) ---------------
template <int F, bool RELU, bool OUT_F32>
__global__ void k_agg(const unsigned short* __restrict__ H, const int2* __restrict__ rec,
                      const int2* __restrict__ rsc, const float* __restrict__ dis,
                      const float* __restrict__ bias, void* __restrict__ out_) {
    constexpr int VPT = F / 64;
    int lane = threadIdx.x & 63;
    int node = blockIdx.x * 4 + (threadIdx.x >> 6);
    if (node >= NODES) return;
    node = __builtin_amdgcn_readfirstlane(node);   // wave-uniform -> SGPR

    const unsigned* H32 = (const unsigned*)H;

    float dn = dis[node];
    float acc0, acc1 = 0.f;
    if (VPT == 2) {
        unsigned hv = H32[node * 64 + lane];
        acc0 = dn * bflo(hv);
        acc1 = dn * bfhi(hv);
    } else {
        acc0 = dn * bf2f(H[node * 64 + lane]);
    }

    int2 rs = rsc[node];
    int beg = rs.x, end = rs.x + rs.y;
    int last = end - 1;
    for (int j = beg; j < end; j += 8) {
        int ss[8]; float nn[8];
#pragma unroll
        for (int q = 0; q < 8; q++) {
            int idx = j + q;
            idx = (idx < last) ? idx : last;           // uniform clamp
            int2 rc = rec[idx];                        // scalar load, broadcast
            ss[q] = rc.x & 0xFFFF;
            nn[q] = (j + q < end) ? __int_as_float(rc.y) : 0.0f;
        }
#pragma unroll
        for (int q = 0; q < 8; q++) nn[q] *= dis[ss[q]];   // broadcast loads
        if (VPT == 2) {
            unsigned hh[8];
#pragma unroll
            for (int q = 0; q < 8; q++) hh[q] = H32[ss[q] * 64 + lane];
#pragma unroll
            for (int q = 0; q < 8; q++) {
                acc0 += nn[q] * bflo(hh[q]);
                acc1 += nn[q] * bfhi(hh[q]);
            }
        } else {
            unsigned short hh[8];
#pragma unroll
            for (int q = 0; q < 8; q++) hh[q] = H[ss[q] * 64 + lane];
#pragma unroll
            for (int q = 0; q < 8; q++) acc0 += nn[q] * bf2f(hh[q]);
        }
    }

    if (OUT_F32) {
        float* out = (float*)out_;
        if (VPT == 2) {
            float x0 = dn * acc0 + bias[lane * 2];
            float x1 = dn * acc1 + bias[lane * 2 + 1];
            if (RELU) { x0 = fmaxf(x0, 0.f); x1 = fmaxf(x1, 0.f); }
            out[(size_t)node * F + lane * 2] = x0;
            out[(size_t)node * F + lane * 2 + 1] = x1;
        } else {
            float x0 = dn * acc0 + bias[lane];
            if (RELU) x0 = fmaxf(x0, 0.f);
            out[(size_t)node * F + lane] = x0;
        }
    } else {
        unsigned short* out = (unsigned short*)out_;
        if (VPT == 2) {
            float x0 = dn * acc0 + bias[lane * 2];
            float x1 = dn * acc1 + bias[lane * 2 + 1];
            if (RELU) { x0 = fmaxf(x0, 0.f); x1 = fmaxf(x1, 0.f); }
            unsigned pk = (unsigned)f2bf(x0) | ((unsigned)f2bf(x1) << 16);
            *(unsigned*)&out[(size_t)node * F + lane * 2] = pk;
        } else {
            float x0 = dn * acc0 + bias[lane];
            if (RELU) x0 = fmaxf(x0, 0.f);
            out[(size_t)node * F + lane] = f2bf(x0);
        }
    }
}

// ---------------- launch ----------------

extern "C" void kernel_launch(void* const* d_in, const int* in_sizes, int n_in,
                              void* d_out, int out_size, void* d_ws, size_t ws_size,
                              hipStream_t stream) {
    const float* x  = (const float*)d_in[0];
    const int*   ei = (const int*)d_in[1];
    const float* w  = (const float*)d_in[2];
    const float* W1 = (const float*)d_in[3];
    const float* b1 = (const float*)d_in[4];
    const float* W2 = (const float*)d_in[5];
    const float* b2 = (const float*)d_in[6];
    const float* W3 = (const float*)d_in[7];
    const float* b3 = (const float*)d_in[8];
    const int* src = ei;
    const int* dst = ei + EDGES;

    char* p = (char*)d_ws;
    auto alloc = [&](size_t n) { char* r = p; p += (n + 511) & ~(size_t)511; return r; };
    unsigned*       hist   = (unsigned*)alloc((size_t)NBUK * NBLK * 4);
    uint2*          cbB    = (uint2*)alloc((size_t)NBLK * NBUKP * 8);
    int2*           brange = (int2*)alloc((size_t)NBUK * 8);
    int*            cursor = (int*)alloc(4);
    int2*           rec    = (int2*)alloc((size_t)EDGES * 8);
    float*          dis    = (float*)alloc(NODES * 4);
    int2*           rsc    = (int2*)alloc((size_t)NODES * 8);
    unsigned short* h      = (unsigned short*)alloc((size_t)NODES * 128 * 2);
    unsigned short* xb     = (unsigned short*)alloc((size_t)NODES * 128 * 2);
    unsigned short* wf1    = (unsigned short*)alloc(256 * 128 * 2);
    unsigned short* wf2    = (unsigned short*)alloc(128 * 128 * 2);
    unsigned short* wf3    = (unsigned short*)alloc(128 * 64 * 2);

    const int TB = 256;
    int nb_gemm = (NTILE + 3) / 4;        // 782
    int nb_agg  = (NODES + 3) / 4;        // 12500

    hipLaunchKernelGGL(k_setup_hist, dim3(NBLK + 28), dim3(TB), 0, stream,
                       dst, hist, cursor, W1, wf1, W2, wf2, W3, wf3);
    hipLaunchKernelGGL(k_hscan, dim3(NBUK), dim3(TB), 0, stream, hist, cbB, brange, cursor);
    hipLaunchKernelGGL(k_sort, dim3(NBLK), dim3(1024), 0, stream, src, dst, w, cbB, rec);
    hipLaunchKernelGGL(k_sub, dim3(NBUK), dim3(TB), 0, stream, rec, brange, dis, rsc);

    // Layer 1
    hipLaunchKernelGGL((k_gemm<256, 128, true>), dim3(nb_gemm), dim3(TB), 0, stream, (const void*)x, (const uint4*)wf1, h);
    hipLaunchKernelGGL((k_agg<128, true, false>), dim3(nb_agg), dim3(TB), 0, stream, h, rec, rsc, dis, b1, (void*)xb);

    // Layer 2
    hipLaunchKernelGGL((k_gemm<128, 128, false>), dim3(nb_gemm), dim3(TB), 0, stream, (const void*)xb, (const uint4*)wf2, h);
    hipLaunchKernelGGL((k_agg<128, true, false>), dim3(nb_agg), dim3(TB), 0, stream, h, rec, rsc, dis, b2, (void*)xb);

    // Layer 3 (no relu, fp32 out)
    hipLaunchKernelGGL((k_gemm<128, 64, false>), dim3(nb_gemm), dim3(TB), 0, stream, (const void*)xb, (const uint4*)wf3, h);
    hipLaunchKernelGGL((k_agg<64, false, true>), dim3(nb_agg), dim3(TB), 0, stream, h, rec, rsc, dis, b3, d_out);
}